// Round 5
// baseline (1264.758 us; speedup 1.0000x reference)
//
#include <hip/hip_runtime.h>

// Dims (from reference): N=100000, E=1600000, D=8, K=1, F=32 everywhere.
#define F 32
#define D 8
#define BKN 512     // nodes per bucket
#define BKSH 9      // log2(BKN)

typedef int iv4 __attribute__((ext_vector_type(4)));

__device__ __forceinline__ unsigned f2bf(float f) {      // fp32 -> bf16 bits (RNE)
    unsigned u = __float_as_uint(f);
    return (u + 0x7fffu + ((u >> 16) & 1u)) >> 16;
}
__device__ __forceinline__ float bf2f(unsigned b) {      // bf16 bits (low 16) -> fp32
    return __uint_as_float(b << 16);
}

// ---------------- transform: xgh = bf16(x@g) ; xr = x@root + b ----------------
__global__ void transform_kernel(const float* __restrict__ x,
                                 const float* __restrict__ g,
                                 const float* __restrict__ root,
                                 const float* __restrict__ b,
                                 unsigned short* __restrict__ xgh,
                                 float* __restrict__ xr,
                                 int N) {
    __shared__ float gs[F * F];
    __shared__ float rs[F * F];
    for (int i = threadIdx.x; i < F * F; i += blockDim.x) {
        gs[i] = g[i];
        rs[i] = root[i];
    }
    __syncthreads();
    int m = threadIdx.x & 31;
    int node = (int)((blockIdx.x * (size_t)blockDim.x + threadIdx.x) >> 5);
    if (node >= N) return;
    float xv = x[(size_t)node * F + m];
    int base = threadIdx.x & 32;
    float accg = 0.f, accr = 0.f;
#pragma unroll
    for (int c = 0; c < F; ++c) {
        float xc = __shfl(xv, base + c, 64);
        accg += xc * gs[c * F + m];
        accr += xc * rs[c * F + m];
    }
    xgh[(size_t)node * F + m] = (unsigned short)f2bf(accg);
    xr[(size_t)node * F + m] = accr + b[m];
}

// ---------------- bucket count ----------------
__global__ void count_kernel(const int* __restrict__ ei, int* __restrict__ bbin,
                             int NB, int E) {
    __shared__ int sh[1024];
    for (int i = threadIdx.x; i < NB; i += blockDim.x) sh[i] = 0;
    __syncthreads();
    for (int e = blockIdx.x * blockDim.x + threadIdx.x; e < E; e += gridDim.x * blockDim.x)
        atomicAdd(&sh[ei[E + e] >> BKSH], 1);
    __syncthreads();
    for (int i = threadIdx.x; i < NB; i += blockDim.x)
        if (sh[i]) atomicAdd(&bbin[i], sh[i]);
}

// ---------------- bucket exclusive scan (1 block of 1024) ----------------
__global__ void bucket_scan_kernel(const int* __restrict__ bbin, int* __restrict__ bbase,
                                   int* __restrict__ bcur, int NB, int E) {
    __shared__ int sh[1024];
    int t = threadIdx.x;
    int v = (t < NB) ? bbin[t] : 0;
    sh[t] = v;
    __syncthreads();
    for (int d = 1; d < 1024; d <<= 1) {
        int u = (t >= d) ? sh[t - d] : 0;
        __syncthreads();
        sh[t] += u;
        __syncthreads();
    }
    int excl = sh[t] - v;
    if (t < NB) { bbase[t] = excl; bcur[t] = excl; }
    if (t == NB) bbase[t] = E;
}

// ---------------- phase 1: bin edges by dst bucket + fused gauss ----------------
// bin[pos] = (src, dst&511, bf16g1 | bf16g2<<16, 0)
__global__ void bin_kernel(const int* __restrict__ ei, const float* __restrict__ ew,
                           const float* __restrict__ mu1, const float* __restrict__ sg1,
                           const float* __restrict__ mu2, const float* __restrict__ sg2,
                           int* __restrict__ bcur, iv4* __restrict__ bin, int E) {
    int e = blockIdx.x * blockDim.x + threadIdx.x;
    if (e >= E) return;
    int src = ei[e];
    int dst = ei[E + e];
    const float4* ew4 = (const float4*)(ew + (size_t)e * D);
    float4 w0 = ew4[0], w1 = ew4[1];
    float w[D] = {w0.x, w0.y, w0.z, w0.w, w1.x, w1.y, w1.z, w1.w};
    float s1 = 0.f, s2 = 0.f;
#pragma unroll
    for (int d = 0; d < D; ++d) {
        float d1 = w[d] - mu1[d];
        s1 -= 0.5f * d1 * d1 / (1e-15f + sg1[d] * sg1[d]);
        float d2 = w[d] - mu2[d];
        s2 -= 0.5f * d2 * d2 / (1e-15f + sg2[d] * sg2[d]);
    }
    unsigned gp = f2bf(expf(s1)) | (f2bf(expf(s2)) << 16);
    int pos = atomicAdd(&bcur[dst >> BKSH], 1);
    iv4 p;
    p.x = src;
    p.y = dst & (BKN - 1);
    p.z = (int)gp;
    p.w = 0;
    __builtin_nontemporal_store(p, &bin[pos]);
}

// ---------------- phase 2: per-bucket CSR build + compact payload ----------------
// one block per bucket; all writes land in an L2-resident ~130KB window
__global__ void csr_kernel(const iv4* __restrict__ bin, const int* __restrict__ bbase,
                           int* __restrict__ off, uint2* __restrict__ edata,
                           int N, int NB) {
    int b = blockIdx.x;
    int ebase = bbase[b], eend = bbase[b + 1];
    int nE = eend - ebase;
    __shared__ int cnt[BKN];
    __shared__ int loff[BKN];
    __shared__ int cur[BKN];
    __shared__ int ps[256];
    int t = threadIdx.x;
    for (int j = t; j < BKN; j += 256) cnt[j] = 0;
    __syncthreads();
    for (int i = t; i < nE; i += 256) atomicAdd(&cnt[bin[ebase + i].y], 1);
    __syncthreads();
    // exclusive scan of 512 counters (2 per thread)
    int a0 = cnt[2 * t], a1 = cnt[2 * t + 1];
    ps[t] = a0 + a1;
    __syncthreads();
    for (int d = 1; d < 256; d <<= 1) {
        int u = (t >= d) ? ps[t - d] : 0;
        __syncthreads();
        ps[t] += u;
        __syncthreads();
    }
    int excl = ps[t] - (a0 + a1);
    loff[2 * t] = excl;
    loff[2 * t + 1] = excl + a0;
    cur[2 * t] = excl;
    cur[2 * t + 1] = excl + a0;
    __syncthreads();
    int nodeBase = b << BKSH;
    for (int j = t; j < BKN; j += 256) {
        int node = nodeBase + j;
        if (node < N) off[node] = ebase + loff[j];
    }
    if (b == NB - 1 && t == 0) off[N] = eend;
    __syncthreads();
    for (int i = t; i < nE; i += 256) {
        iv4 p = bin[ebase + i];                 // L2 hit (same block just wrote it)
        int pos = ebase + atomicAdd(&cur[p.y], 1);
        uint2 q;
        q.x = (unsigned)p.x;
        q.y = (unsigned)p.z;
        edata[pos] = q;                          // 8B store in L2-resident window
    }
}

// ---------------- gather-aggregate + fused finalize ----------------
// WHICH==1 -> gauss in low bf16, WHICH==2 -> high bf16
template <int WHICH>
__global__ void aggregate_kernel(const int* __restrict__ off,
                                 const uint2* __restrict__ edata,
                                 const unsigned short* __restrict__ xgh,
                                 const float* __restrict__ xr,
                                 float* __restrict__ out, int N) {
    int m = threadIdx.x & 31;
    int node = (int)((blockIdx.x * (size_t)blockDim.x + threadIdx.x) >> 5);
    if (node >= N) return;
    int base = threadIdx.x & 32;
    int s0 = off[node], s1 = off[node + 1];
    int deg = s1 - s0;
    float acc = 0.f;
    int i = s0;
    for (; i + 32 <= s1; i += 32) {            // full chunks: unrolled, high ILP
        uint2 ed = edata[i + m];
        int sv = (int)ed.x;
        float gv = (WHICH == 1) ? bf2f(ed.y & 0xffffu) : __uint_as_float(ed.y & 0xffff0000u);
#pragma unroll
        for (int j = 0; j < 32; ++j) {
            int s = __shfl(sv, base + j, 64);
            float g = __shfl(gv, base + j, 64);
            acc += bf2f(xgh[(size_t)s * F + m]) * g;
        }
    }
    if (i < s1) {                               // tail
        int rem = s1 - i;
        int sv = 0;
        float gv = 0.f;
        if (i + m < s1) {
            uint2 ed = edata[i + m];
            sv = (int)ed.x;
            gv = (WHICH == 1) ? bf2f(ed.y & 0xffffu) : __uint_as_float(ed.y & 0xffff0000u);
        }
        for (int j = 0; j < rem; ++j) {
            int s = __shfl(sv, base + j, 64);
            float g = __shfl(gv, base + j, 64);
            acc += bf2f(xgh[(size_t)s * F + m]) * g;
        }
    }
    float o = (deg > 0) ? acc / (float)deg : 0.f;
    out[(size_t)node * F + m] = o + xr[(size_t)node * F + m];
}

extern "C" void kernel_launch(void* const* d_in, const int* in_sizes, int n_in,
                              void* d_out, int out_size, void* d_ws, size_t ws_size,
                              hipStream_t stream) {
    const int*   ei   = (const int*)d_in[0];     // (2, E) int32
    const float* ew   = (const float*)d_in[1];   // (E, 8)
    const float* x    = (const float*)d_in[2];   // (N, 32)
    const float* g1   = (const float*)d_in[3];
    const float* mu1  = (const float*)d_in[4];
    const float* sg1  = (const float*)d_in[5];
    const float* r1   = (const float*)d_in[6];
    const float* b1   = (const float*)d_in[7];
    const float* g2   = (const float*)d_in[8];
    const float* mu2  = (const float*)d_in[9];
    const float* sg2  = (const float*)d_in[10];
    const float* r2   = (const float*)d_in[11];
    const float* b2   = (const float*)d_in[12];
    float* out = (float*)d_out;

    const int E = in_sizes[0] / 2;
    const int N = in_sizes[2] / F;
    const size_t NF = (size_t)N * F;
    const int NB = (N + BKN - 1) / BKN;          // 196 buckets for N=100000

    // workspace layout
    iv4*            bin   = (iv4*)d_ws;                  // E * 16B
    uint2*          edata = (uint2*)(bin + E);           // E * 8B
    float*          xr    = (float*)(edata + E);         // NF * 4B
    unsigned short* xgh   = (unsigned short*)(xr + NF);  // NF * 2B
    int*            off   = (int*)(xgh + NF);            // N+1
    int*            bbin  = off + N + 1;                 // NB
    int*            bbase = bbin + NB;                   // NB+1
    int*            bcur  = bbase + NB + 1;              // NB
    float*          h     = out;                          // layer-1 output in d_out

    const int BT = 256;
    const int blk_node = (int)((NF + BT - 1) / BT);
    const int blk_edge = (E + BT - 1) / BT;

    // ---- build bucketed CSR (once; shared by both layers) ----
    (void)hipMemsetAsync(bbin, 0, NB * sizeof(int), stream);
    count_kernel<<<1024, BT, 0, stream>>>(ei, bbin, NB, E);
    bucket_scan_kernel<<<1, 1024, 0, stream>>>(bbin, bbase, bcur, NB, E);
    bin_kernel<<<blk_edge, BT, 0, stream>>>(ei, ew, mu1, sg1, mu2, sg2, bcur, bin, E);
    csr_kernel<<<NB, BT, 0, stream>>>(bin, bbase, off, edata, N, NB);

    // ---- layer 1 ----
    transform_kernel<<<blk_node, BT, 0, stream>>>(x, g1, r1, b1, xgh, xr, N);
    aggregate_kernel<1><<<blk_node, BT, 0, stream>>>(off, edata, xgh, xr, h, N);

    // ---- layer 2 ----
    transform_kernel<<<blk_node, BT, 0, stream>>>(h, g2, r2, b2, xgh, xr, N);
    aggregate_kernel<2><<<blk_node, BT, 0, stream>>>(off, edata, xgh, xr, out, N);
}

// Round 6
// 431.020 us; speedup vs baseline: 2.9343x; 2.9343x over previous
//
#include <hip/hip_runtime.h>

// Dims (from reference): N=100000, E=1600000, D=8, K=1, F=32 everywhere.
#define F 32
#define D 8
#define BKN 512     // nodes per bucket
#define BKSH 9      // log2(BKN)
#define EPT 8       // edges per thread in bin_kernel (2048 per block)

typedef int iv4 __attribute__((ext_vector_type(4)));

__device__ __forceinline__ unsigned f2bf(float f) {      // fp32 -> bf16 bits (RNE)
    unsigned u = __float_as_uint(f);
    return (u + 0x7fffu + ((u >> 16) & 1u)) >> 16;
}
__device__ __forceinline__ float bf2f(unsigned b) {      // bf16 bits (low 16) -> fp32
    return __uint_as_float(b << 16);
}

// ---------------- transform: xgh = bf16(x@g) ; xr = x@root + b ----------------
__global__ void transform_kernel(const float* __restrict__ x,
                                 const float* __restrict__ g,
                                 const float* __restrict__ root,
                                 const float* __restrict__ b,
                                 unsigned short* __restrict__ xgh,
                                 float* __restrict__ xr,
                                 int N) {
    __shared__ float gs[F * F];
    __shared__ float rs[F * F];
    for (int i = threadIdx.x; i < F * F; i += blockDim.x) {
        gs[i] = g[i];
        rs[i] = root[i];
    }
    __syncthreads();
    int m = threadIdx.x & 31;
    int node = (int)((blockIdx.x * (size_t)blockDim.x + threadIdx.x) >> 5);
    if (node >= N) return;
    float xv = x[(size_t)node * F + m];
    int base = threadIdx.x & 32;
    float accg = 0.f, accr = 0.f;
#pragma unroll
    for (int c = 0; c < F; ++c) {
        float xc = __shfl(xv, base + c, 64);
        accg += xc * gs[c * F + m];
        accr += xc * rs[c * F + m];
    }
    xgh[(size_t)node * F + m] = (unsigned short)f2bf(accg);
    xr[(size_t)node * F + m] = accr + b[m];
}

// ---------------- bucket count ----------------
__global__ void count_kernel(const int* __restrict__ ei, int* __restrict__ bbin,
                             int NB, int E) {
    __shared__ int sh[256];
    for (int i = threadIdx.x; i < NB; i += blockDim.x) sh[i] = 0;
    __syncthreads();
    for (int e = blockIdx.x * blockDim.x + threadIdx.x; e < E; e += gridDim.x * blockDim.x)
        atomicAdd(&sh[ei[E + e] >> BKSH], 1);
    __syncthreads();
    for (int i = threadIdx.x; i < NB; i += blockDim.x)
        if (sh[i]) atomicAdd(&bbin[i], sh[i]);
}

// ---------------- bucket exclusive scan (1 block of 256; NB<=256) ----------------
__global__ void bucket_scan_kernel(const int* __restrict__ bbin, int* __restrict__ bbase,
                                   int* __restrict__ bcur, int NB, int E) {
    __shared__ int sh[256];
    int t = threadIdx.x;
    int v = (t < NB) ? bbin[t] : 0;
    sh[t] = v;
    __syncthreads();
    for (int d = 1; d < 256; d <<= 1) {
        int u = (t >= d) ? sh[t - d] : 0;
        __syncthreads();
        sh[t] += u;
        __syncthreads();
    }
    int excl = sh[t] - v;
    if (t < NB) { bbase[t] = excl; bcur[t] = excl; }
    if (t == NB) bbase[t] = E;
}

// ---------------- phase 1: bin edges by dst bucket + fused gauss ----------------
// Block-aggregated reservation: LDS histogram -> one global atomic per
// (block,bucket) reserving a contiguous chunk -> LDS-ranked scatter.
// bin[pos] = (src, dst&511, bf16g1 | bf16g2<<16, 0)
__global__ void bin_kernel(const int* __restrict__ ei, const float* __restrict__ ew,
                           const float* __restrict__ mu1, const float* __restrict__ sg1,
                           const float* __restrict__ mu2, const float* __restrict__ sg2,
                           int* __restrict__ bcur, iv4* __restrict__ bin, int NB, int E) {
    __shared__ int hist[256];
    __shared__ int base[256];
    int t = threadIdx.x;
    if (t < NB) hist[t] = 0;
    __syncthreads();

    int e0 = blockIdx.x * (256 * EPT) + t;
    int srcs[EPT], dsts[EPT];
    unsigned gps[EPT];
#pragma unroll
    for (int k = 0; k < EPT; ++k) {
        int e = e0 + k * 256;
        dsts[k] = -1;
        if (e < E) {
            srcs[k] = ei[e];
            int dst = ei[E + e];
            dsts[k] = dst;
            const float4* ew4 = (const float4*)(ew + (size_t)e * D);
            float4 w0 = ew4[0], w1 = ew4[1];
            float w[D] = {w0.x, w0.y, w0.z, w0.w, w1.x, w1.y, w1.z, w1.w};
            float s1 = 0.f, s2 = 0.f;
#pragma unroll
            for (int d = 0; d < D; ++d) {
                float d1 = w[d] - mu1[d];
                s1 -= 0.5f * d1 * d1 / (1e-15f + sg1[d] * sg1[d]);
                float d2 = w[d] - mu2[d];
                s2 -= 0.5f * d2 * d2 / (1e-15f + sg2[d] * sg2[d]);
            }
            gps[k] = f2bf(expf(s1)) | (f2bf(expf(s2)) << 16);
            atomicAdd(&hist[dst >> BKSH], 1);
        }
    }
    __syncthreads();
    if (t < NB) {
        int c = hist[t];
        base[t] = c ? atomicAdd(&bcur[t], c) : 0;   // one chunk reservation/bucket
    }
    __syncthreads();
    if (t < NB) hist[t] = 0;                        // reuse as local cursor
    __syncthreads();
#pragma unroll
    for (int k = 0; k < EPT; ++k) {
        if (dsts[k] >= 0) {
            int bk = dsts[k] >> BKSH;
            int pos = base[bk] + atomicAdd(&hist[bk], 1);
            iv4 p;
            p.x = srcs[k];
            p.y = dsts[k] & (BKN - 1);
            p.z = (int)gps[k];
            p.w = 0;
            __builtin_nontemporal_store(p, &bin[pos]);
        }
    }
}

// ---------------- phase 2: per-bucket CSR build + compact payload ----------------
__global__ void csr_kernel(const iv4* __restrict__ bin, const int* __restrict__ bbase,
                           int* __restrict__ off, uint2* __restrict__ edata,
                           int N, int NB) {
    int b = blockIdx.x;
    int ebase = bbase[b], eend = bbase[b + 1];
    int nE = eend - ebase;
    __shared__ int cnt[BKN];
    __shared__ int loff[BKN];
    __shared__ int cur[BKN];
    __shared__ int ps[256];
    int t = threadIdx.x;
    for (int j = t; j < BKN; j += 256) cnt[j] = 0;
    __syncthreads();
    for (int i = t; i < nE; i += 256) atomicAdd(&cnt[bin[ebase + i].y], 1);
    __syncthreads();
    int a0 = cnt[2 * t], a1 = cnt[2 * t + 1];
    ps[t] = a0 + a1;
    __syncthreads();
    for (int d = 1; d < 256; d <<= 1) {
        int u = (t >= d) ? ps[t - d] : 0;
        __syncthreads();
        ps[t] += u;
        __syncthreads();
    }
    int excl = ps[t] - (a0 + a1);
    loff[2 * t] = excl;
    loff[2 * t + 1] = excl + a0;
    cur[2 * t] = excl;
    cur[2 * t + 1] = excl + a0;
    __syncthreads();
    int nodeBase = b << BKSH;
    for (int j = t; j < BKN; j += 256) {
        int node = nodeBase + j;
        if (node < N) off[node] = ebase + loff[j];
    }
    if (b == NB - 1 && t == 0) off[N] = eend;
    __syncthreads();
    for (int i = t; i < nE; i += 256) {
        iv4 p = bin[ebase + i];
        int pos = ebase + atomicAdd(&cur[p.y], 1);
        uint2 q;
        q.x = (unsigned)p.x;
        q.y = (unsigned)p.z;
        edata[pos] = q;
    }
}

// ---------------- gather-aggregate + fused finalize ----------------
template <int WHICH>
__global__ void aggregate_kernel(const int* __restrict__ off,
                                 const uint2* __restrict__ edata,
                                 const unsigned short* __restrict__ xgh,
                                 const float* __restrict__ xr,
                                 float* __restrict__ out, int N) {
    int m = threadIdx.x & 31;
    int node = (int)((blockIdx.x * (size_t)blockDim.x + threadIdx.x) >> 5);
    if (node >= N) return;
    int base = threadIdx.x & 32;
    int s0 = off[node], s1 = off[node + 1];
    int deg = s1 - s0;
    float acc = 0.f;
    int i = s0;
    for (; i + 32 <= s1; i += 32) {
        uint2 ed = edata[i + m];
        int sv = (int)ed.x;
        float gv = (WHICH == 1) ? bf2f(ed.y & 0xffffu) : __uint_as_float(ed.y & 0xffff0000u);
#pragma unroll
        for (int j = 0; j < 32; ++j) {
            int s = __shfl(sv, base + j, 64);
            float g = __shfl(gv, base + j, 64);
            acc += bf2f(xgh[(size_t)s * F + m]) * g;
        }
    }
    if (i < s1) {
        int rem = s1 - i;
        int sv = 0;
        float gv = 0.f;
        if (i + m < s1) {
            uint2 ed = edata[i + m];
            sv = (int)ed.x;
            gv = (WHICH == 1) ? bf2f(ed.y & 0xffffu) : __uint_as_float(ed.y & 0xffff0000u);
        }
        for (int j = 0; j < rem; ++j) {
            int s = __shfl(sv, base + j, 64);
            float g = __shfl(gv, base + j, 64);
            acc += bf2f(xgh[(size_t)s * F + m]) * g;
        }
    }
    float o = (deg > 0) ? acc / (float)deg : 0.f;
    out[(size_t)node * F + m] = o + xr[(size_t)node * F + m];
}

extern "C" void kernel_launch(void* const* d_in, const int* in_sizes, int n_in,
                              void* d_out, int out_size, void* d_ws, size_t ws_size,
                              hipStream_t stream) {
    const int*   ei   = (const int*)d_in[0];     // (2, E) int32
    const float* ew   = (const float*)d_in[1];   // (E, 8)
    const float* x    = (const float*)d_in[2];   // (N, 32)
    const float* g1   = (const float*)d_in[3];
    const float* mu1  = (const float*)d_in[4];
    const float* sg1  = (const float*)d_in[5];
    const float* r1   = (const float*)d_in[6];
    const float* b1   = (const float*)d_in[7];
    const float* g2   = (const float*)d_in[8];
    const float* mu2  = (const float*)d_in[9];
    const float* sg2  = (const float*)d_in[10];
    const float* r2   = (const float*)d_in[11];
    const float* b2   = (const float*)d_in[12];
    float* out = (float*)d_out;

    const int E = in_sizes[0] / 2;
    const int N = in_sizes[2] / F;
    const size_t NF = (size_t)N * F;
    const int NB = (N + BKN - 1) / BKN;          // 196 buckets for N=100000

    // workspace layout
    iv4*            bin   = (iv4*)d_ws;                  // E * 16B
    uint2*          edata = (uint2*)(bin + E);           // E * 8B
    float*          xr    = (float*)(edata + E);         // NF * 4B
    unsigned short* xgh   = (unsigned short*)(xr + NF);  // NF * 2B
    int*            off   = (int*)(xgh + NF);            // N+1
    int*            bbin  = off + N + 1;                 // NB
    int*            bbase = bbin + NB;                   // NB+1
    int*            bcur  = bbase + NB + 1;              // NB
    float*          h     = out;                          // layer-1 output in d_out

    const int BT = 256;
    const int blk_node = (int)((NF + BT - 1) / BT);
    const int blk_bin  = (E + BT * EPT - 1) / (BT * EPT);

    // ---- build bucketed CSR (once; shared by both layers) ----
    (void)hipMemsetAsync(bbin, 0, NB * sizeof(int), stream);
    count_kernel<<<1024, BT, 0, stream>>>(ei, bbin, NB, E);
    bucket_scan_kernel<<<1, BT, 0, stream>>>(bbin, bbase, bcur, NB, E);
    bin_kernel<<<blk_bin, BT, 0, stream>>>(ei, ew, mu1, sg1, mu2, sg2, bcur, bin, NB, E);
    csr_kernel<<<NB, BT, 0, stream>>>(bin, bbase, off, edata, N, NB);

    // ---- layer 1 ----
    transform_kernel<<<blk_node, BT, 0, stream>>>(x, g1, r1, b1, xgh, xr, N);
    aggregate_kernel<1><<<blk_node, BT, 0, stream>>>(off, edata, xgh, xr, h, N);

    // ---- layer 2 ----
    transform_kernel<<<blk_node, BT, 0, stream>>>(h, g2, r2, b2, xgh, xr, N);
    aggregate_kernel<2><<<blk_node, BT, 0, stream>>>(off, edata, xgh, xr, out, N);
}